// Round 13
// baseline (329.087 us; speedup 1.0000x reference)
//
#include <hip/hip_runtime.h>
#include <hip/hip_fp16.h>

#define LN_EPS 1e-5f
#define D 128
#define TN 16      // nodes per tile = nodes per bucket
#define NT 8       // nodes per 128-thread group in GEMM+LN stage
#define BCAP 768   // bucket capacity (avg 512 = 16 nodes x 32 avg in-deg; +11 sigma)

// ---------------------------------------------------------------------------
// K1: bucket-bin edges by dst>>4 (dense writes) + out-degree FF histogram
//     + feat->fp16 convert (unscaled, independent) folded in to hide latency.
__global__ __launch_bounds__(256) void k_build(const int* __restrict__ ei, int E,
        int* __restrict__ cnt_out, int* __restrict__ bcnt,
        unsigned int* __restrict__ bkt,
        const float4* __restrict__ feat4, ushort4* __restrict__ feat_h, int total) {
    int tid = blockIdx.x * blockDim.x + threadIdx.x;
    int stride = gridDim.x * blockDim.x;

    auto edges = [&]() {
        int E4 = E >> 2;
        const int4* src4 = (const int4*)ei;
        const int4* dst4 = (const int4*)(ei + E);
        for (int i = tid; i < E4; i += stride) {
            int4 s = src4[i];
            int4 d = dst4[i];
            atomicAdd(&cnt_out[s.x], 1);
            atomicAdd(&cnt_out[s.y], 1);
            atomicAdd(&cnt_out[s.z], 1);
            atomicAdd(&cnt_out[s.w], 1);
            int p0 = atomicAdd(&bcnt[d.x >> 4], 1);
            int p1 = atomicAdd(&bcnt[d.y >> 4], 1);
            int p2 = atomicAdd(&bcnt[d.z >> 4], 1);
            int p3 = atomicAdd(&bcnt[d.w >> 4], 1);
            if (p0 < BCAP) bkt[(size_t)(d.x >> 4) * BCAP + p0] = (unsigned)s.x | ((unsigned)(d.x & 15) << 16);
            if (p1 < BCAP) bkt[(size_t)(d.y >> 4) * BCAP + p1] = (unsigned)s.y | ((unsigned)(d.y & 15) << 16);
            if (p2 < BCAP) bkt[(size_t)(d.z >> 4) * BCAP + p2] = (unsigned)s.z | ((unsigned)(d.z & 15) << 16);
            if (p3 < BCAP) bkt[(size_t)(d.w >> 4) * BCAP + p3] = (unsigned)s.w | ((unsigned)(d.w & 15) << 16);
        }
        for (int e = (E4 << 2) + tid; e < E; e += stride) {
            int s = ei[e], dd = ei[E + e];
            atomicAdd(&cnt_out[s], 1);
            int p = atomicAdd(&bcnt[dd >> 4], 1);
            if (p < BCAP) bkt[(size_t)(dd >> 4) * BCAP + p] = (unsigned)s | ((unsigned)(dd & 15) << 16);
        }
    };
    auto convert = [&]() {
        for (int i = tid; i < total; i += stride) {
            float4 f = feat4[i];
            __half2 lo = __floats2half2_rn(f.x, f.y);
            __half2 hi = __floats2half2_rn(f.z, f.w);
            ushort4 u;
            u.x = __half_as_ushort(__low2half(lo));
            u.y = __half_as_ushort(__high2half(lo));
            u.z = __half_as_ushort(__low2half(hi));
            u.w = __half_as_ushort(__high2half(hi));
            feat_h[i] = u;
        }
    };
    if (blockIdx.x & 1) { edges(); convert(); }
    else                { convert(); edges(); }
}

// K2: rs_out = rsqrt(max(deg_out,1)); transpose W -> Wt
__global__ __launch_bounds__(256) void k_rs(const int* __restrict__ cnt_out,
                                            float* __restrict__ rs_out,
                                            const float* __restrict__ W,
                                            float* __restrict__ Wt, int N) {
    int i = blockIdx.x * blockDim.x + threadIdx.x;
    if (i < N) rs_out[i] = rsqrtf((float)max(cnt_out[i], 1));
    if (i < D * D) {
        int r = i >> 7, c = i & 127;
        Wt[c * D + r] = W[i];
    }
}

// K3: fused per-bucket LDS-bin ; gather(rs_out-scaled fp16) ; GEMM ; LN ; ReLU
__global__ __launch_bounds__(256) void k_fused(
        const int* __restrict__ bcnt, const unsigned int* __restrict__ bkt,
        const float* __restrict__ rs_out,
        const __half2* __restrict__ feat_h, const float* __restrict__ Wt,
        const float* __restrict__ bias, const float* __restrict__ gamma,
        const float* __restrict__ beta, const float* __restrict__ feat,
        float* __restrict__ out, int N) {
    __shared__ float aggT[TN][D];            // 8 KB
    __shared__ float redS[2][2][NT];
    __shared__ float redQ[2][2][NT];
    __shared__ unsigned int braw[BCAP];      // staged bucket edges, 3 KB
    __shared__ unsigned short blist[BCAP];   // srcs grouped by local node, 1.5 KB
    __shared__ int bstart[TN + 1];
    __shared__ int bfill[TN];
    __shared__ int bdeg[TN];

    int tid  = threadIdx.x;
    int wv   = tid >> 6;          // wave 0..3
    int lane = tid & 63;
    int g    = tid >> 7;          // GEMM group 0/1
    int d    = tid & 127;         // output dim
    int w2   = (tid >> 6) & 1;    // wave within group

    float bd  = bias[d];
    float gd  = gamma[d];
    float btd = beta[d];

    int ntiles = (N + TN - 1) / TN;
    for (int t = blockIdx.x; t < ntiles; t += gridDim.x) {
        int nbase = t * TN;
        __syncthreads();   // previous tile's readers done

        // ---- stage bucket & histogram by local node (dst & 15)
        if (tid < TN) { bdeg[tid] = 0; bfill[tid] = 0; }
        __syncthreads();
        int ecnt = min(bcnt[t], BCAP);
        for (int j = tid; j < ecnt; j += 256) {
            unsigned int v = bkt[(size_t)t * BCAP + j];   // coalesced
            braw[j] = v;
            atomicAdd(&bdeg[v >> 16], 1);                 // LDS atomic
        }
        __syncthreads();
        if (tid == 0) {
            int run = 0;
            #pragma unroll
            for (int i = 0; i < TN; ++i) { bstart[i] = run; run += bdeg[i]; }
            bstart[TN] = run;
        }
        __syncthreads();
        for (int j = tid; j < ecnt; j += 256) {
            unsigned int v = braw[j];
            int node = v >> 16;
            int slot = bstart[node] + atomicAdd(&bfill[node], 1);
            blist[slot] = (unsigned short)(v & 0xFFFF);
        }
        __syncthreads();

        // ---- gather: wave wv builds rows wv*4 .. wv*4+3 of the tile
        for (int i = 0; i < 4; ++i) {
            int li = wv * 4 + i;
            int n  = nbase + li;
            float2 acc = make_float2(0.0f, 0.0f);
            if (n < N) {
                int deg = bdeg[li];
                int st  = bstart[li];
                int m8  = deg & ~7;
                int j   = 0;
                for (; j < m8; j += 8) {
                    int ss[8];
                    #pragma unroll
                    for (int k = 0; k < 8; ++k) ss[k] = blist[st + j + k];  // LDS broadcast
                    float rr[8];
                    #pragma unroll
                    for (int k = 0; k < 8; ++k) rr[k] = rs_out[ss[k]];      // L2 broadcast
                    __half2 hh[8];
                    #pragma unroll
                    for (int k = 0; k < 8; ++k)
                        hh[k] = feat_h[(size_t)ss[k] * 64 + lane];          // 8 in flight
                    #pragma unroll
                    for (int k = 0; k < 8; ++k) {
                        float2 f = __half22float2(hh[k]);
                        acc.x = fmaf(f.x, rr[k], acc.x);
                        acc.y = fmaf(f.y, rr[k], acc.y);
                    }
                }
                for (; j < deg; ++j) {
                    int s = blist[st + j];
                    float r = rs_out[s];
                    float2 f = __half22float2(feat_h[(size_t)s * 64 + lane]);
                    acc.x = fmaf(f.x, r, acc.x);
                    acc.y = fmaf(f.y, r, acc.y);
                }
            }
            ((float2*)aggT[li])[lane] = acc;   // 2-way bank alias: free
        }
        __syncthreads();

        // ---- GEMM + residual + LayerNorm + ReLU stage
        float acc[NT];
        #pragma unroll
        for (int j = 0; j < NT; ++j) acc[j] = 0.0f;

        #pragma unroll 4
        for (int k = 0; k < D; ++k) {
            float w = Wt[(size_t)k * D + d];          // coalesced, L1-hit
            #pragma unroll
            for (int j = 0; j < NT; ++j)
                acc[j] = fmaf(aggT[g * NT + j][k], w, acc[j]);  // LDS broadcast
        }

        float r[NT], s[NT], q[NT];
        #pragma unroll
        for (int j = 0; j < NT; ++j) {
            int li = g * NT + j;
            int n  = nbase + li;
            float ri = 0.0f;
            if (n < N) {
                float rsin = rsqrtf((float)max(bdeg[li], 1));
                ri = (acc[j] + bd) * rsin + feat[(size_t)n * D + d];
            }
            r[j] = ri;
            s[j] = ri;
            q[j] = ri * ri;
        }

        #pragma unroll
        for (int j = 0; j < NT; ++j) {
            for (int off = 32; off > 0; off >>= 1) {
                s[j] += __shfl_down(s[j], off);
                q[j] += __shfl_down(q[j], off);
            }
        }
        if (lane == 0) {
            #pragma unroll
            for (int j = 0; j < NT; ++j) { redS[g][w2][j] = s[j]; redQ[g][w2][j] = q[j]; }
        }
        __syncthreads();

        #pragma unroll
        for (int j = 0; j < NT; ++j) {
            int n = nbase + g * NT + j;
            if (n < N) {
                float S  = redS[g][0][j] + redS[g][1][j];
                float Q  = redQ[g][0][j] + redQ[g][1][j];
                float mu = S * (1.0f / 128.0f);
                float var = Q * (1.0f / 128.0f) - mu * mu;
                float v = (r[j] - mu) * rsqrtf(var + LN_EPS) * gd + btd;
                out[(size_t)n * D + d] = fmaxf(v, 0.0f);
            }
        }
    }
}

// ---------------------------------------------------------------------------
extern "C" void kernel_launch(void* const* d_in, const int* in_sizes, int n_in,
                              void* d_out, int out_size, void* d_ws, size_t ws_size,
                              hipStream_t stream) {
    const float* feat  = (const float*)d_in[0];
    const int*   ei    = (const int*)  d_in[1];
    const float* W     = (const float*)d_in[2];
    const float* bias  = (const float*)d_in[3];
    const float* gamma = (const float*)d_in[4];
    const float* beta  = (const float*)d_in[5];
    float* out = (float*)d_out;

    const int N  = in_sizes[0] / D;
    const int E  = in_sizes[1] / 2;
    const int NB = (N + TN - 1) / TN;   // buckets = output tiles

    // workspace layout (4B words):
    // cnt_out[Np] | bcnt[NBp] | rs_out[Np] | Wt[D*D] |
    // bkt[NB*BCAP u32] | feat_h[N*D/2 words]        (~23 MB)
    const size_t Np  = ((size_t)N + 1023) & ~(size_t)1023;
    const size_t NBp = ((size_t)NB + 1023) & ~(size_t)1023;
    int*   cnt_out = (int*)d_ws;
    int*   bcnt    = cnt_out + Np;
    float* rs_out  = (float*)(bcnt + NBp);
    float* Wt      = rs_out + Np;
    unsigned int* bkt = (unsigned int*)(Wt + D * D);
    ushort4* feat_h   = (ushort4*)(bkt + (size_t)NB * BCAP);

    hipMemsetAsync(d_ws, 0, (Np + NBp) * sizeof(int), stream);  // zero cnt_out + bcnt

    k_build<<<2048, 256, 0, stream>>>(ei, E, cnt_out, bcnt, bkt,
                                      (const float4*)feat, feat_h, N * 32);
    int nblk = (max(N, D * D) + 255) / 256;
    k_rs<<<nblk, 256, 0, stream>>>(cnt_out, rs_out, W, Wt, N);
    k_fused<<<NB, 256, 0, stream>>>(bcnt, bkt, rs_out,
                                    (const __half2*)feat_h, Wt, bias, gamma,
                                    beta, feat, out, N);
}

// Round 14
// 233.948 us; speedup vs baseline: 1.4067x; 1.4067x over previous
//
#include <hip/hip_runtime.h>
#include <hip/hip_fp16.h>

#define LN_EPS 1e-5f
#define D 128
#define TN 16      // nodes per tile = nodes per bucket
#define NT 8       // nodes per 128-thread group in GEMM+LN stage
#define BCAP 768   // bucket capacity (avg 512 = 16 nodes x 32 avg in-deg; +11 sigma)
#define MAXB 4096  // max buckets in LDS (N <= 65536, already required by u16 src)
#define BBLK 64    // build blocks: chunk = E/64 = ~25K edges -> ~8 edges/bucket

// ---------------------------------------------------------------------------
// K1: bucket-bin via LDS-aggregated reservation (200K ret-atomics, not 1.6M)
//     + out-degree histogram with no-return atomics.
__global__ __launch_bounds__(256) void k_build(const int* __restrict__ ei, int E,
        int* __restrict__ cnt_out, int* __restrict__ bcnt,
        unsigned int* __restrict__ bkt, int NB) {
    __shared__ int h[MAXB];     // per-block bucket counts, then unused
    __shared__ int cur[MAXB];   // global write cursors after reservation
    int tid = threadIdx.x;
    int E4 = E >> 2;
    int chunk4 = (E4 + gridDim.x - 1) / gridDim.x;
    int lo4 = blockIdx.x * chunk4;
    int hi4 = min(E4, lo4 + chunk4);
    const int4* src4 = (const int4*)ei;
    const int4* dst4 = (const int4*)(ei + E);
    bool last = (blockIdx.x == gridDim.x - 1);

    for (int k = tid; k < NB; k += 256) h[k] = 0;
    __syncthreads();

    // ---- pass 1: LDS bucket histogram + global out-degree (fire-and-forget)
    for (int i = lo4 + tid; i < hi4; i += 256) {
        int4 s = src4[i];
        int4 d = dst4[i];
        atomicAdd(&cnt_out[s.x], 1);
        atomicAdd(&cnt_out[s.y], 1);
        atomicAdd(&cnt_out[s.z], 1);
        atomicAdd(&cnt_out[s.w], 1);
        atomicAdd(&h[d.x >> 4], 1);
        atomicAdd(&h[d.y >> 4], 1);
        atomicAdd(&h[d.z >> 4], 1);
        atomicAdd(&h[d.w >> 4], 1);
    }
    if (last) {
        for (int e = (E4 << 2) + tid; e < E; e += 256) {
            atomicAdd(&cnt_out[ei[e]], 1);
            atomicAdd(&h[ei[E + e] >> 4], 1);
        }
    }
    __syncthreads();

    // ---- reservation: one return-atomic per nonzero (block,bucket)
    for (int k = tid; k < NB; k += 256) {
        int c = h[k];
        cur[k] = c ? atomicAdd(&bcnt[k], c) : 0;
    }
    __syncthreads();

    // ---- pass 2: scatter via LDS cursors (L2-hot re-read of own chunk)
    for (int i = lo4 + tid; i < hi4; i += 256) {
        int4 s = src4[i];
        int4 d = dst4[i];
        int p0 = atomicAdd(&cur[d.x >> 4], 1);
        int p1 = atomicAdd(&cur[d.y >> 4], 1);
        int p2 = atomicAdd(&cur[d.z >> 4], 1);
        int p3 = atomicAdd(&cur[d.w >> 4], 1);
        if (p0 < BCAP) bkt[(size_t)(d.x >> 4) * BCAP + p0] = (unsigned)s.x | ((unsigned)(d.x & 15) << 16);
        if (p1 < BCAP) bkt[(size_t)(d.y >> 4) * BCAP + p1] = (unsigned)s.y | ((unsigned)(d.y & 15) << 16);
        if (p2 < BCAP) bkt[(size_t)(d.z >> 4) * BCAP + p2] = (unsigned)s.z | ((unsigned)(d.z & 15) << 16);
        if (p3 < BCAP) bkt[(size_t)(d.w >> 4) * BCAP + p3] = (unsigned)s.w | ((unsigned)(d.w & 15) << 16);
    }
    if (last) {
        for (int e = (E4 << 2) + tid; e < E; e += 256) {
            int s = ei[e], dd = ei[E + e];
            int p = atomicAdd(&cur[dd >> 4], 1);
            if (p < BCAP) bkt[(size_t)(dd >> 4) * BCAP + p] = (unsigned)s | ((unsigned)(dd & 15) << 16);
        }
    }
}

// K2: rs_out = rsqrt(max(deg_out,1)); transpose W -> Wt
__global__ __launch_bounds__(256) void k_rs(const int* __restrict__ cnt_out,
                                            float* __restrict__ rs_out,
                                            const float* __restrict__ W,
                                            float* __restrict__ Wt, int N) {
    int i = blockIdx.x * blockDim.x + threadIdx.x;
    if (i < N) rs_out[i] = rsqrtf((float)max(cnt_out[i], 1));
    if (i < D * D) {
        int r = i >> 7, c = i & 127;
        Wt[c * D + r] = W[i];
    }
}

// K3: feat_h[n][d] = (half)(feat[n][d] * rs_out[n])  (pre-scaled fp16)
__global__ __launch_bounds__(256) void k_prep(const float4* __restrict__ feat4,
                                              const float* __restrict__ rs_out,
                                              ushort4* __restrict__ feat_h,
                                              int total /* N*32 */) {
    int stride = gridDim.x * blockDim.x;
    for (int i = blockIdx.x * blockDim.x + threadIdx.x; i < total; i += stride) {
        int n = i >> 5;
        float rs = rs_out[n];
        float4 f = feat4[i];
        __half2 lo = __floats2half2_rn(f.x * rs, f.y * rs);
        __half2 hi = __floats2half2_rn(f.z * rs, f.w * rs);
        ushort4 u;
        u.x = __half_as_ushort(__low2half(lo));
        u.y = __half_as_ushort(__high2half(lo));
        u.z = __half_as_ushort(__low2half(hi));
        u.w = __half_as_ushort(__high2half(hi));
        feat_h[i] = u;
    }
}

// K4: fused per-bucket LDS-bin ; gather (pre-scaled fp16) ; GEMM ; LN ; ReLU
__global__ __launch_bounds__(256) void k_fused(
        const int* __restrict__ bcnt, const unsigned int* __restrict__ bkt,
        const __half2* __restrict__ feat_h, const float* __restrict__ Wt,
        const float* __restrict__ bias, const float* __restrict__ gamma,
        const float* __restrict__ beta, const float* __restrict__ feat,
        float* __restrict__ out, int N) {
    __shared__ float aggT[TN][D];            // 8 KB
    __shared__ float redS[2][2][NT];
    __shared__ float redQ[2][2][NT];
    __shared__ unsigned int braw[BCAP];      // staged bucket edges, 3 KB
    __shared__ unsigned short blist[BCAP];   // srcs grouped by local node, 1.5 KB
    __shared__ int bstart[TN + 1];
    __shared__ int bfill[TN];
    __shared__ int bdeg[TN];

    int tid  = threadIdx.x;
    int wv   = tid >> 6;          // wave 0..3
    int lane = tid & 63;
    int g    = tid >> 7;          // GEMM group 0/1
    int d    = tid & 127;         // output dim
    int w2   = (tid >> 6) & 1;    // wave within group

    float bd  = bias[d];
    float gd  = gamma[d];
    float btd = beta[d];

    int ntiles = (N + TN - 1) / TN;
    for (int t = blockIdx.x; t < ntiles; t += gridDim.x) {
        int nbase = t * TN;
        __syncthreads();   // previous tile's readers done

        // ---- stage bucket & histogram by local node (dst & 15)
        if (tid < TN) { bdeg[tid] = 0; bfill[tid] = 0; }
        __syncthreads();
        int ecnt = min(bcnt[t], BCAP);
        for (int j = tid; j < ecnt; j += 256) {
            unsigned int v = bkt[(size_t)t * BCAP + j];   // coalesced
            braw[j] = v;
            atomicAdd(&bdeg[v >> 16], 1);                 // LDS atomic
        }
        __syncthreads();
        if (tid == 0) {
            int run = 0;
            #pragma unroll
            for (int i = 0; i < TN; ++i) { bstart[i] = run; run += bdeg[i]; }
            bstart[TN] = run;
        }
        __syncthreads();
        for (int j = tid; j < ecnt; j += 256) {
            unsigned int v = braw[j];
            int node = v >> 16;
            int slot = bstart[node] + atomicAdd(&bfill[node], 1);
            blist[slot] = (unsigned short)(v & 0xFFFF);
        }
        __syncthreads();

        // ---- gather: wave wv builds rows wv*4 .. wv*4+3 of the tile
        for (int i = 0; i < 4; ++i) {
            int li = wv * 4 + i;
            int n  = nbase + li;
            float2 acc = make_float2(0.0f, 0.0f);
            if (n < N) {
                int deg = bdeg[li];
                int st  = bstart[li];
                int m8  = deg & ~7;
                int j   = 0;
                for (; j < m8; j += 8) {
                    int ss[8];
                    #pragma unroll
                    for (int k = 0; k < 8; ++k) ss[k] = blist[st + j + k];  // LDS broadcast
                    __half2 hh[8];
                    #pragma unroll
                    for (int k = 0; k < 8; ++k)
                        hh[k] = feat_h[(size_t)ss[k] * 64 + lane];          // 8 in flight
                    #pragma unroll
                    for (int k = 0; k < 8; ++k) {
                        float2 f = __half22float2(hh[k]);
                        acc.x += f.x; acc.y += f.y;
                    }
                }
                for (; j < deg; ++j) {
                    int s = blist[st + j];
                    float2 f = __half22float2(feat_h[(size_t)s * 64 + lane]);
                    acc.x += f.x; acc.y += f.y;
                }
            }
            ((float2*)aggT[li])[lane] = acc;   // 2-way bank alias: free
        }
        __syncthreads();

        // ---- GEMM + residual + LayerNorm + ReLU stage
        float acc[NT];
        #pragma unroll
        for (int j = 0; j < NT; ++j) acc[j] = 0.0f;

        #pragma unroll 4
        for (int k = 0; k < D; ++k) {
            float w = Wt[(size_t)k * D + d];          // coalesced, L1-hit
            #pragma unroll
            for (int j = 0; j < NT; ++j)
                acc[j] = fmaf(aggT[g * NT + j][k], w, acc[j]);  // LDS broadcast
        }

        float r[NT], s[NT], q[NT];
        #pragma unroll
        for (int j = 0; j < NT; ++j) {
            int li = g * NT + j;
            int n  = nbase + li;
            float ri = 0.0f;
            if (n < N) {
                float rsin = rsqrtf((float)max(bdeg[li], 1));
                ri = (acc[j] + bd) * rsin + feat[(size_t)n * D + d];
            }
            r[j] = ri;
            s[j] = ri;
            q[j] = ri * ri;
        }

        #pragma unroll
        for (int j = 0; j < NT; ++j) {
            for (int off = 32; off > 0; off >>= 1) {
                s[j] += __shfl_down(s[j], off);
                q[j] += __shfl_down(q[j], off);
            }
        }
        if (lane == 0) {
            #pragma unroll
            for (int j = 0; j < NT; ++j) { redS[g][w2][j] = s[j]; redQ[g][w2][j] = q[j]; }
        }
        __syncthreads();

        #pragma unroll
        for (int j = 0; j < NT; ++j) {
            int n = nbase + g * NT + j;
            if (n < N) {
                float S  = redS[g][0][j] + redS[g][1][j];
                float Q  = redQ[g][0][j] + redQ[g][1][j];
                float mu = S * (1.0f / 128.0f);
                float var = Q * (1.0f / 128.0f) - mu * mu;
                float v = (r[j] - mu) * rsqrtf(var + LN_EPS) * gd + btd;
                out[(size_t)n * D + d] = fmaxf(v, 0.0f);
            }
        }
    }
}

// ---------------------------------------------------------------------------
extern "C" void kernel_launch(void* const* d_in, const int* in_sizes, int n_in,
                              void* d_out, int out_size, void* d_ws, size_t ws_size,
                              hipStream_t stream) {
    const float* feat  = (const float*)d_in[0];
    const int*   ei    = (const int*)  d_in[1];
    const float* W     = (const float*)d_in[2];
    const float* bias  = (const float*)d_in[3];
    const float* gamma = (const float*)d_in[4];
    const float* beta  = (const float*)d_in[5];
    float* out = (float*)d_out;

    const int N  = in_sizes[0] / D;
    const int E  = in_sizes[1] / 2;
    const int NB = (N + TN - 1) / TN;   // buckets = output tiles (<= MAXB)

    // workspace layout (4B words):
    // cnt_out[Np] | bcnt[NBp] | rs_out[Np] | Wt[D*D] |
    // bkt[NB*BCAP u32] | feat_h[N*D/2 words]        (~23 MB)
    const size_t Np  = ((size_t)N + 1023) & ~(size_t)1023;
    const size_t NBp = ((size_t)NB + 1023) & ~(size_t)1023;
    int*   cnt_out = (int*)d_ws;
    int*   bcnt    = cnt_out + Np;
    float* rs_out  = (float*)(bcnt + NBp);
    float* Wt      = rs_out + Np;
    unsigned int* bkt = (unsigned int*)(Wt + D * D);
    ushort4* feat_h   = (ushort4*)(bkt + (size_t)NB * BCAP);

    hipMemsetAsync(d_ws, 0, (Np + NBp) * sizeof(int), stream);  // zero cnt_out + bcnt

    k_build<<<BBLK, 256, 0, stream>>>(ei, E, cnt_out, bcnt, bkt, NB);
    int nblk = (max(N, D * D) + 255) / 256;
    k_rs<<<nblk, 256, 0, stream>>>(cnt_out, rs_out, W, Wt, N);
    k_prep<<<2048, 256, 0, stream>>>((const float4*)feat, rs_out, feat_h, N * 32);
    k_fused<<<NB, 256, 0, stream>>>(bcnt, bkt,
                                    (const __half2*)feat_h, Wt, bias, gamma,
                                    beta, feat, out, N);
}

// Round 16
// 218.046 us; speedup vs baseline: 1.5093x; 1.0729x over previous
//
#include <hip/hip_runtime.h>
#include <hip/hip_fp16.h>

#define LN_EPS 1e-5f
#define D 128
#define TN 16      // nodes per tile = nodes per bucket
#define NT 8       // nodes per 128-thread group in GEMM+LN stage
#define BCAP 768   // bucket capacity (avg 512 = 16 nodes x 32 avg in-deg; +11 sigma)
#define MAXB 4096  // max buckets in LDS (N <= 65536, already required by u16 src)
#define BBLK 128   // binning blocks
#define HBLK 2048  // histogram blocks

// ---------------------------------------------------------------------------
// K1: two roles in one launch.
//   blocks [0,BBLK):       LDS bucket histogram -> reserve -> scatter (binning)
//   blocks [BBLK,+HBLK):   cnt_out no-return histogram at high occupancy
__global__ __launch_bounds__(256) void k_build(const int* __restrict__ ei, int E,
        int* __restrict__ cnt_out, int* __restrict__ bcnt,
        unsigned int* __restrict__ bkt, int NB) {
    __shared__ int h[MAXB];     // binning role only
    __shared__ int cur[MAXB];
    int tid = threadIdx.x;
    int E4 = E >> 2;
    const int4* src4 = (const int4*)ei;
    const int4* dst4 = (const int4*)(ei + E);

    if (blockIdx.x >= BBLK) {
        // ---- histogram role: out-degree counts, grid-stride, fire-and-forget
        int gtid = (blockIdx.x - BBLK) * 256 + tid;
        int gstride = (gridDim.x - BBLK) * 256;
        for (int i = gtid; i < E4; i += gstride) {
            int4 s = src4[i];
            atomicAdd(&cnt_out[s.x], 1);
            atomicAdd(&cnt_out[s.y], 1);
            atomicAdd(&cnt_out[s.z], 1);
            atomicAdd(&cnt_out[s.w], 1);
        }
        for (int e = (E4 << 2) + gtid; e < E; e += gstride) {
            atomicAdd(&cnt_out[ei[e]], 1);
        }
        return;
    }

    // ---- binning role: own contiguous chunk
    int chunk4 = (E4 + BBLK - 1) / BBLK;
    int lo4 = blockIdx.x * chunk4;
    int hi4 = min(E4, lo4 + chunk4);
    bool last = (blockIdx.x == BBLK - 1);

    for (int k = tid; k < NB; k += 256) h[k] = 0;
    __syncthreads();

    // pass 1: LDS bucket histogram
    for (int i = lo4 + tid; i < hi4; i += 256) {
        int4 d = dst4[i];
        atomicAdd(&h[d.x >> 4], 1);
        atomicAdd(&h[d.y >> 4], 1);
        atomicAdd(&h[d.z >> 4], 1);
        atomicAdd(&h[d.w >> 4], 1);
    }
    if (last) {
        for (int e = (E4 << 2) + tid; e < E; e += 256)
            atomicAdd(&h[ei[E + e] >> 4], 1);
    }
    __syncthreads();

    // reservation: one return-atomic per nonzero (block,bucket)
    for (int k = tid; k < NB; k += 256) {
        int c = h[k];
        cur[k] = c ? atomicAdd(&bcnt[k], c) : 0;
    }
    __syncthreads();

    // pass 2: scatter via LDS cursors (L2-hot re-read of own chunk)
    for (int i = lo4 + tid; i < hi4; i += 256) {
        int4 s = src4[i];
        int4 d = dst4[i];
        int p0 = atomicAdd(&cur[d.x >> 4], 1);
        int p1 = atomicAdd(&cur[d.y >> 4], 1);
        int p2 = atomicAdd(&cur[d.z >> 4], 1);
        int p3 = atomicAdd(&cur[d.w >> 4], 1);
        if (p0 < BCAP) bkt[(size_t)(d.x >> 4) * BCAP + p0] = (unsigned)s.x | ((unsigned)(d.x & 15) << 16);
        if (p1 < BCAP) bkt[(size_t)(d.y >> 4) * BCAP + p1] = (unsigned)s.y | ((unsigned)(d.y & 15) << 16);
        if (p2 < BCAP) bkt[(size_t)(d.z >> 4) * BCAP + p2] = (unsigned)s.z | ((unsigned)(d.z & 15) << 16);
        if (p3 < BCAP) bkt[(size_t)(d.w >> 4) * BCAP + p3] = (unsigned)s.w | ((unsigned)(d.w & 15) << 16);
    }
    if (last) {
        for (int e = (E4 << 2) + tid; e < E; e += 256) {
            int s = ei[e], dd = ei[E + e];
            int p = atomicAdd(&cur[dd >> 4], 1);
            if (p < BCAP) bkt[(size_t)(dd >> 4) * BCAP + p] = (unsigned)s | ((unsigned)(dd & 15) << 16);
        }
    }
}

// K2: rs_out = rsqrt(max(deg_out,1)); transpose W -> Wt
__global__ __launch_bounds__(256) void k_rs(const int* __restrict__ cnt_out,
                                            float* __restrict__ rs_out,
                                            const float* __restrict__ W,
                                            float* __restrict__ Wt, int N) {
    int i = blockIdx.x * blockDim.x + threadIdx.x;
    if (i < N) rs_out[i] = rsqrtf((float)max(cnt_out[i], 1));
    if (i < D * D) {
        int r = i >> 7, c = i & 127;
        Wt[c * D + r] = W[i];
    }
}

// K3: feat_h[n][d] = (half)(feat[n][d] * rs_out[n])  (pre-scaled fp16)
__global__ __launch_bounds__(256) void k_prep(const float4* __restrict__ feat4,
                                              const float* __restrict__ rs_out,
                                              ushort4* __restrict__ feat_h,
                                              int total /* N*32 */) {
    int stride = gridDim.x * blockDim.x;
    for (int i = blockIdx.x * blockDim.x + threadIdx.x; i < total; i += stride) {
        int n = i >> 5;
        float rs = rs_out[n];
        float4 f = feat4[i];
        __half2 lo = __floats2half2_rn(f.x * rs, f.y * rs);
        __half2 hi = __floats2half2_rn(f.z * rs, f.w * rs);
        ushort4 u;
        u.x = __half_as_ushort(__low2half(lo));
        u.y = __half_as_ushort(__high2half(lo));
        u.z = __half_as_ushort(__low2half(hi));
        u.w = __half_as_ushort(__high2half(hi));
        feat_h[i] = u;
    }
}

// K4: fused per-bucket LDS-bin ; gather (pre-scaled fp16) ; GEMM ; LN ; ReLU
__global__ __launch_bounds__(256) void k_fused(
        const int* __restrict__ bcnt, const unsigned int* __restrict__ bkt,
        const __half2* __restrict__ feat_h, const float* __restrict__ Wt,
        const float* __restrict__ bias, const float* __restrict__ gamma,
        const float* __restrict__ beta, const float* __restrict__ feat,
        float* __restrict__ out, int N) {
    __shared__ float aggT[TN][D];            // 8 KB
    __shared__ float redS[2][2][NT];
    __shared__ float redQ[2][2][NT];
    __shared__ unsigned int braw[BCAP];      // staged bucket edges, 3 KB
    __shared__ unsigned short blist[BCAP];   // srcs grouped by local node, 1.5 KB
    __shared__ int bstart[TN + 1];
    __shared__ int bfill[TN];
    __shared__ int bdeg[TN];

    int tid  = threadIdx.x;
    int wv   = tid >> 6;          // wave 0..3
    int lane = tid & 63;
    int g    = tid >> 7;          // GEMM group 0/1
    int d    = tid & 127;         // output dim
    int w2   = (tid >> 6) & 1;    // wave within group

    float bd  = bias[d];
    float gd  = gamma[d];
    float btd = beta[d];

    int ntiles = (N + TN - 1) / TN;
    for (int t = blockIdx.x; t < ntiles; t += gridDim.x) {
        int nbase = t * TN;
        __syncthreads();   // previous tile's readers done

        // ---- stage bucket & histogram by local node (dst & 15)
        if (tid < TN) { bdeg[tid] = 0; bfill[tid] = 0; }
        __syncthreads();
        int ecnt = min(bcnt[t], BCAP);
        for (int j = tid; j < ecnt; j += 256) {
            unsigned int v = bkt[(size_t)t * BCAP + j];   // coalesced
            braw[j] = v;
            atomicAdd(&bdeg[v >> 16], 1);                 // LDS atomic
        }
        __syncthreads();
        if (tid == 0) {
            int run = 0;
            #pragma unroll
            for (int i = 0; i < TN; ++i) { bstart[i] = run; run += bdeg[i]; }
            bstart[TN] = run;
        }
        __syncthreads();
        for (int j = tid; j < ecnt; j += 256) {
            unsigned int v = braw[j];
            int node = v >> 16;
            int slot = bstart[node] + atomicAdd(&bfill[node], 1);
            blist[slot] = (unsigned short)(v & 0xFFFF);
        }
        __syncthreads();

        // ---- gather: wave wv builds rows wv*4 .. wv*4+3 of the tile
        for (int i = 0; i < 4; ++i) {
            int li = wv * 4 + i;
            int n  = nbase + li;
            float2 acc = make_float2(0.0f, 0.0f);
            if (n < N) {
                int deg = bdeg[li];
                int st  = bstart[li];
                int m8  = deg & ~7;
                int j   = 0;
                for (; j < m8; j += 8) {
                    int ss[8];
                    #pragma unroll
                    for (int k = 0; k < 8; ++k) ss[k] = blist[st + j + k];  // LDS broadcast
                    __half2 hh[8];
                    #pragma unroll
                    for (int k = 0; k < 8; ++k)
                        hh[k] = feat_h[(size_t)ss[k] * 64 + lane];          // 8 in flight
                    #pragma unroll
                    for (int k = 0; k < 8; ++k) {
                        float2 f = __half22float2(hh[k]);
                        acc.x += f.x; acc.y += f.y;
                    }
                }
                for (; j < deg; ++j) {
                    int s = blist[st + j];
                    float2 f = __half22float2(feat_h[(size_t)s * 64 + lane]);
                    acc.x += f.x; acc.y += f.y;
                }
            }
            ((float2*)aggT[li])[lane] = acc;   // 2-way bank alias: free
        }
        __syncthreads();

        // ---- GEMM + residual + LayerNorm + ReLU stage
        float acc[NT];
        #pragma unroll
        for (int j = 0; j < NT; ++j) acc[j] = 0.0f;

        #pragma unroll 4
        for (int k = 0; k < D; ++k) {
            float w = Wt[(size_t)k * D + d];          // coalesced, L1-hit
            #pragma unroll
            for (int j = 0; j < NT; ++j)
                acc[j] = fmaf(aggT[g * NT + j][k], w, acc[j]);  // LDS broadcast
        }

        float r[NT], s[NT], q[NT];
        #pragma unroll
        for (int j = 0; j < NT; ++j) {
            int li = g * NT + j;
            int n  = nbase + li;
            float ri = 0.0f;
            if (n < N) {
                float rsin = rsqrtf((float)max(bdeg[li], 1));
                ri = (acc[j] + bd) * rsin + feat[(size_t)n * D + d];
            }
            r[j] = ri;
            s[j] = ri;
            q[j] = ri * ri;
        }

        #pragma unroll
        for (int j = 0; j < NT; ++j) {
            for (int off = 32; off > 0; off >>= 1) {
                s[j] += __shfl_down(s[j], off);
                q[j] += __shfl_down(q[j], off);
            }
        }
        if (lane == 0) {
            #pragma unroll
            for (int j = 0; j < NT; ++j) { redS[g][w2][j] = s[j]; redQ[g][w2][j] = q[j]; }
        }
        __syncthreads();

        #pragma unroll
        for (int j = 0; j < NT; ++j) {
            int n = nbase + g * NT + j;
            if (n < N) {
                float S  = redS[g][0][j] + redS[g][1][j];
                float Q  = redQ[g][0][j] + redQ[g][1][j];
                float mu = S * (1.0f / 128.0f);
                float var = Q * (1.0f / 128.0f) - mu * mu;
                float v = (r[j] - mu) * rsqrtf(var + LN_EPS) * gd + btd;
                out[(size_t)n * D + d] = fmaxf(v, 0.0f);
            }
        }
    }
}

// ---------------------------------------------------------------------------
extern "C" void kernel_launch(void* const* d_in, const int* in_sizes, int n_in,
                              void* d_out, int out_size, void* d_ws, size_t ws_size,
                              hipStream_t stream) {
    const float* feat  = (const float*)d_in[0];
    const int*   ei    = (const int*)  d_in[1];
    const float* W     = (const float*)d_in[2];
    const float* bias  = (const float*)d_in[3];
    const float* gamma = (const float*)d_in[4];
    const float* beta  = (const float*)d_in[5];
    float* out = (float*)d_out;

    const int N  = in_sizes[0] / D;
    const int E  = in_sizes[1] / 2;
    const int NB = (N + TN - 1) / TN;   // buckets = output tiles (<= MAXB)

    // workspace layout (4B words):
    // cnt_out[Np] | bcnt[NBp] | rs_out[Np] | Wt[D*D] |
    // bkt[NB*BCAP u32] | feat_h[N*D/2 words]        (~23 MB)
    const size_t Np  = ((size_t)N + 1023) & ~(size_t)1023;
    const size_t NBp = ((size_t)NB + 1023) & ~(size_t)1023;
    int*   cnt_out = (int*)d_ws;
    int*   bcnt    = cnt_out + Np;
    float* rs_out  = (float*)(bcnt + NBp);
    float* Wt      = rs_out + Np;
    unsigned int* bkt = (unsigned int*)(Wt + D * D);
    ushort4* feat_h   = (ushort4*)(bkt + (size_t)NB * BCAP);

    hipMemsetAsync(d_ws, 0, (Np + NBp) * sizeof(int), stream);  // zero cnt_out + bcnt

    k_build<<<BBLK + HBLK, 256, 0, stream>>>(ei, E, cnt_out, bcnt, bkt, NB);
    int nblk = (max(N, D * D) + 255) / 256;
    k_rs<<<nblk, 256, 0, stream>>>(cnt_out, rs_out, W, Wt, N);
    k_prep<<<2048, 256, 0, stream>>>((const float4*)feat, rs_out, feat_h, N * 32);
    k_fused<<<NB, 256, 0, stream>>>(bcnt, bkt,
                                    (const __half2*)feat_h, Wt, bias, gamma,
                                    beta, feat, out, N);
}

// Round 17
// 214.421 us; speedup vs baseline: 1.5348x; 1.0169x over previous
//
#include <hip/hip_runtime.h>
#include <hip/hip_fp16.h>

#define LN_EPS 1e-5f
#define D 128
#define TN 16      // nodes per tile = nodes per bucket
#define NT 8       // nodes per 128-thread group in GEMM+LN stage
#define BCAP 768   // bucket capacity (avg 512 = 16 nodes x 32 avg in-deg; +11 sigma)
#define MAXB 4096  // max buckets in LDS (N <= 65536, already required by u16 src)
#define BBLK 128   // binning blocks
#define HBLK 2048  // histogram blocks

// ---------------------------------------------------------------------------
// K1: two roles in one launch.
//   blocks [0,BBLK):       LDS bucket histogram -> reserve -> scatter (binning)
//   blocks [BBLK,+HBLK):   cnt_out no-return histogram at high occupancy
__global__ __launch_bounds__(256) void k_build(const int* __restrict__ ei, int E,
        int* __restrict__ cnt_out, int* __restrict__ bcnt,
        unsigned int* __restrict__ bkt, int NB) {
    __shared__ int h[MAXB];     // binning role only
    __shared__ int cur[MAXB];
    int tid = threadIdx.x;
    int E4 = E >> 2;
    const int4* src4 = (const int4*)ei;
    const int4* dst4 = (const int4*)(ei + E);

    if (blockIdx.x >= BBLK) {
        // ---- histogram role: out-degree counts, grid-stride, fire-and-forget
        int gtid = (blockIdx.x - BBLK) * 256 + tid;
        int gstride = (gridDim.x - BBLK) * 256;
        for (int i = gtid; i < E4; i += gstride) {
            int4 s = src4[i];
            atomicAdd(&cnt_out[s.x], 1);
            atomicAdd(&cnt_out[s.y], 1);
            atomicAdd(&cnt_out[s.z], 1);
            atomicAdd(&cnt_out[s.w], 1);
        }
        for (int e = (E4 << 2) + gtid; e < E; e += gstride) {
            atomicAdd(&cnt_out[ei[e]], 1);
        }
        return;
    }

    // ---- binning role: own contiguous chunk
    int chunk4 = (E4 + BBLK - 1) / BBLK;
    int lo4 = blockIdx.x * chunk4;
    int hi4 = min(E4, lo4 + chunk4);
    bool last = (blockIdx.x == BBLK - 1);

    for (int k = tid; k < NB; k += 256) h[k] = 0;
    __syncthreads();

    // pass 1: LDS bucket histogram
    for (int i = lo4 + tid; i < hi4; i += 256) {
        int4 d = dst4[i];
        atomicAdd(&h[d.x >> 4], 1);
        atomicAdd(&h[d.y >> 4], 1);
        atomicAdd(&h[d.z >> 4], 1);
        atomicAdd(&h[d.w >> 4], 1);
    }
    if (last) {
        for (int e = (E4 << 2) + tid; e < E; e += 256)
            atomicAdd(&h[ei[E + e] >> 4], 1);
    }
    __syncthreads();

    // reservation: one return-atomic per nonzero (block,bucket)
    for (int k = tid; k < NB; k += 256) {
        int c = h[k];
        cur[k] = c ? atomicAdd(&bcnt[k], c) : 0;
    }
    __syncthreads();

    // pass 2: scatter via LDS cursors (L2-hot re-read of own chunk)
    for (int i = lo4 + tid; i < hi4; i += 256) {
        int4 s = src4[i];
        int4 d = dst4[i];
        int p0 = atomicAdd(&cur[d.x >> 4], 1);
        int p1 = atomicAdd(&cur[d.y >> 4], 1);
        int p2 = atomicAdd(&cur[d.z >> 4], 1);
        int p3 = atomicAdd(&cur[d.w >> 4], 1);
        if (p0 < BCAP) bkt[(size_t)(d.x >> 4) * BCAP + p0] = (unsigned)s.x | ((unsigned)(d.x & 15) << 16);
        if (p1 < BCAP) bkt[(size_t)(d.y >> 4) * BCAP + p1] = (unsigned)s.y | ((unsigned)(d.y & 15) << 16);
        if (p2 < BCAP) bkt[(size_t)(d.z >> 4) * BCAP + p2] = (unsigned)s.z | ((unsigned)(d.z & 15) << 16);
        if (p3 < BCAP) bkt[(size_t)(d.w >> 4) * BCAP + p3] = (unsigned)s.w | ((unsigned)(d.w & 15) << 16);
    }
    if (last) {
        for (int e = (E4 << 2) + tid; e < E; e += 256) {
            int s = ei[e], dd = ei[E + e];
            int p = atomicAdd(&cur[dd >> 4], 1);
            if (p < BCAP) bkt[(size_t)(dd >> 4) * BCAP + p] = (unsigned)s | ((unsigned)(dd & 15) << 16);
        }
    }
}

// K2: rs_out = rsqrt(max(deg_out,1)); pack Wt4[k4*D+d] = W[d][4k4..4k4+3]
__global__ __launch_bounds__(256) void k_rs(const int* __restrict__ cnt_out,
                                            float* __restrict__ rs_out,
                                            const float* __restrict__ W,
                                            float4* __restrict__ Wt4, int N) {
    int i = blockIdx.x * blockDim.x + threadIdx.x;
    if (i < N) rs_out[i] = rsqrtf((float)max(cnt_out[i], 1));
    if (i < D * D / 4) {
        int d  = i & 127;        // output dim
        int k4 = i >> 7;         // k quad
        Wt4[(size_t)k4 * D + d] = ((const float4*)W)[(size_t)d * 32 + k4];
    }
}

// K3: feat_h[n][d] = (half)(feat[n][d] * rs_out[n])  (pre-scaled fp16)
__global__ __launch_bounds__(256) void k_prep(const float4* __restrict__ feat4,
                                              const float* __restrict__ rs_out,
                                              ushort4* __restrict__ feat_h,
                                              int total /* N*32 */) {
    int stride = gridDim.x * blockDim.x;
    for (int i = blockIdx.x * blockDim.x + threadIdx.x; i < total; i += stride) {
        int n = i >> 5;
        float rs = rs_out[n];
        float4 f = feat4[i];
        __half2 lo = __floats2half2_rn(f.x * rs, f.y * rs);
        __half2 hi = __floats2half2_rn(f.z * rs, f.w * rs);
        ushort4 u;
        u.x = __half_as_ushort(__low2half(lo));
        u.y = __half_as_ushort(__high2half(lo));
        u.z = __half_as_ushort(__low2half(hi));
        u.w = __half_as_ushort(__high2half(hi));
        feat_h[i] = u;
    }
}

// K4: fused per-bucket LDS-bin ; gather (pre-scaled fp16) ; GEMM(f4) ; LN ; ReLU
__global__ __launch_bounds__(256) void k_fused(
        const int* __restrict__ bcnt, const unsigned int* __restrict__ bkt,
        const __half2* __restrict__ feat_h, const float4* __restrict__ Wt4,
        const float* __restrict__ bias, const float* __restrict__ gamma,
        const float* __restrict__ beta, const float* __restrict__ feat,
        float* __restrict__ out, int N) {
    __shared__ float aggT[TN][D];            // 8 KB
    __shared__ float redS[2][2][NT];
    __shared__ float redQ[2][2][NT];
    __shared__ unsigned int braw[BCAP];      // staged bucket edges, 3 KB
    __shared__ unsigned short blist[BCAP];   // srcs grouped by local node, 1.5 KB
    __shared__ int bstart[TN + 1];
    __shared__ int bfill[TN];
    __shared__ int bdeg[TN];

    int tid  = threadIdx.x;
    int wv   = tid >> 6;          // wave 0..3
    int lane = tid & 63;
    int g    = tid >> 7;          // GEMM group 0/1
    int d    = tid & 127;         // output dim
    int w2   = (tid >> 6) & 1;    // wave within group

    float bd  = bias[d];
    float gd  = gamma[d];
    float btd = beta[d];

    int ntiles = (N + TN - 1) / TN;
    for (int t = blockIdx.x; t < ntiles; t += gridDim.x) {
        int nbase = t * TN;
        __syncthreads();   // previous tile's readers done

        // ---- stage bucket & histogram by local node (dst & 15)
        if (tid < TN) { bdeg[tid] = 0; bfill[tid] = 0; }
        __syncthreads();
        int ecnt = min(bcnt[t], BCAP);
        for (int j = tid; j < ecnt; j += 256) {
            unsigned int v = bkt[(size_t)t * BCAP + j];   // coalesced
            braw[j] = v;
            atomicAdd(&bdeg[v >> 16], 1);                 // LDS atomic
        }
        __syncthreads();
        if (tid == 0) {
            int run = 0;
            #pragma unroll
            for (int i = 0; i < TN; ++i) { bstart[i] = run; run += bdeg[i]; }
            bstart[TN] = run;
        }
        __syncthreads();
        for (int j = tid; j < ecnt; j += 256) {
            unsigned int v = braw[j];
            int node = v >> 16;
            int slot = bstart[node] + atomicAdd(&bfill[node], 1);
            blist[slot] = (unsigned short)(v & 0xFFFF);
        }
        __syncthreads();

        // ---- gather: wave wv builds rows wv*4 .. wv*4+3 of the tile
        for (int i = 0; i < 4; ++i) {
            int li = wv * 4 + i;
            int n  = nbase + li;
            float2 acc = make_float2(0.0f, 0.0f);
            if (n < N) {
                int deg = bdeg[li];
                int st  = bstart[li];
                int m8  = deg & ~7;
                int j   = 0;
                for (; j < m8; j += 8) {
                    int ss[8];
                    #pragma unroll
                    for (int k = 0; k < 8; ++k) ss[k] = blist[st + j + k];  // LDS broadcast
                    __half2 hh[8];
                    #pragma unroll
                    for (int k = 0; k < 8; ++k)
                        hh[k] = feat_h[(size_t)ss[k] * 64 + lane];          // 8 in flight
                    #pragma unroll
                    for (int k = 0; k < 8; ++k) {
                        float2 f = __half22float2(hh[k]);
                        acc.x += f.x; acc.y += f.y;
                    }
                }
                for (; j < deg; ++j) {
                    int s = blist[st + j];
                    float2 f = __half22float2(feat_h[(size_t)s * 64 + lane]);
                    acc.x += f.x; acc.y += f.y;
                }
            }
            ((float2*)aggT[li])[lane] = acc;   // 2-way bank alias: free
        }
        __syncthreads();

        // ---- GEMM (float4 LDS broadcast + packed W) + residual + LN + ReLU
        float acc[NT];
        #pragma unroll
        for (int j = 0; j < NT; ++j) acc[j] = 0.0f;

        #pragma unroll 4
        for (int k4 = 0; k4 < D / 4; ++k4) {
            float4 w = Wt4[(size_t)k4 * D + d];     // coalesced dwordx4, L1-hit
            #pragma unroll
            for (int j = 0; j < NT; ++j) {
                float4 a = *(const float4*)&aggT[g * NT + j][4 * k4];  // ds_read_b128 broadcast
                acc[j] = fmaf(a.x, w.x, fmaf(a.y, w.y, fmaf(a.z, w.z, fmaf(a.w, w.w, acc[j]))));
            }
        }

        float r[NT], s[NT], q[NT];
        #pragma unroll
        for (int j = 0; j < NT; ++j) {
            int li = g * NT + j;
            int n  = nbase + li;
            float ri = 0.0f;
            if (n < N) {
                float rsin = rsqrtf((float)max(bdeg[li], 1));
                ri = (acc[j] + bd) * rsin + feat[(size_t)n * D + d];
            }
            r[j] = ri;
            s[j] = ri;
            q[j] = ri * ri;
        }

        #pragma unroll
        for (int j = 0; j < NT; ++j) {
            for (int off = 32; off > 0; off >>= 1) {
                s[j] += __shfl_down(s[j], off);
                q[j] += __shfl_down(q[j], off);
            }
        }
        if (lane == 0) {
            #pragma unroll
            for (int j = 0; j < NT; ++j) { redS[g][w2][j] = s[j]; redQ[g][w2][j] = q[j]; }
        }
        __syncthreads();

        #pragma unroll
        for (int j = 0; j < NT; ++j) {
            int n = nbase + g * NT + j;
            if (n < N) {
                float S  = redS[g][0][j] + redS[g][1][j];
                float Q  = redQ[g][0][j] + redQ[g][1][j];
                float mu = S * (1.0f / 128.0f);
                float var = Q * (1.0f / 128.0f) - mu * mu;
                float v = (r[j] - mu) * rsqrtf(var + LN_EPS) * gd + btd;
                out[(size_t)n * D + d] = fmaxf(v, 0.0f);
            }
        }
    }
}

// ---------------------------------------------------------------------------
extern "C" void kernel_launch(void* const* d_in, const int* in_sizes, int n_in,
                              void* d_out, int out_size, void* d_ws, size_t ws_size,
                              hipStream_t stream) {
    const float* feat  = (const float*)d_in[0];
    const int*   ei    = (const int*)  d_in[1];
    const float* W     = (const float*)d_in[2];
    const float* bias  = (const float*)d_in[3];
    const float* gamma = (const float*)d_in[4];
    const float* beta  = (const float*)d_in[5];
    float* out = (float*)d_out;

    const int N  = in_sizes[0] / D;
    const int E  = in_sizes[1] / 2;
    const int NB = (N + TN - 1) / TN;   // buckets = output tiles (<= MAXB)

    // workspace layout (4B words):
    // cnt_out[Np] | bcnt[NBp] | rs_out[Np] | Wt4[D*D] |
    // bkt[NB*BCAP u32] | feat_h[N*D/2 words]        (~23 MB)
    const size_t Np  = ((size_t)N + 1023) & ~(size_t)1023;
    const size_t NBp = ((size_t)NB + 1023) & ~(size_t)1023;
    int*   cnt_out = (int*)d_ws;
    int*   bcnt    = cnt_out + Np;
    float* rs_out  = (float*)(bcnt + NBp);
    float4* Wt4    = (float4*)(rs_out + Np);
    unsigned int* bkt = (unsigned int*)((float*)Wt4 + D * D);
    ushort4* feat_h   = (ushort4*)(bkt + (size_t)NB * BCAP);

    hipMemsetAsync(d_ws, 0, (Np + NBp) * sizeof(int), stream);  // zero cnt_out + bcnt

    k_build<<<BBLK + HBLK, 256, 0, stream>>>(ei, E, cnt_out, bcnt, bkt, NB);
    int nblk = (max(N, D * D) + 255) / 256;
    k_rs<<<nblk, 256, 0, stream>>>(cnt_out, rs_out, W, Wt4, N);
    k_prep<<<2048, 256, 0, stream>>>((const float4*)feat, rs_out, feat_h, N * 32);
    k_fused<<<NB, 256, 0, stream>>>(bcnt, bkt,
                                    (const __half2*)feat_h, Wt4, bias, gamma,
                                    beta, feat, out, N);
}

// Round 18
// 208.588 us; speedup vs baseline: 1.5777x; 1.0280x over previous
//
#include <hip/hip_runtime.h>
#include <hip/hip_fp16.h>

#define LN_EPS 1e-5f
#define D 128
#define TN 16      // nodes per tile = nodes per bucket
#define BCAP 768   // bucket capacity (avg 512 = 16 nodes x 32 avg in-deg; +11 sigma)
#define MAXB 4096  // max buckets in LDS (N <= 65536, already required by u16 src)
#define BBLK 128   // binning blocks
#define HBLK 2048  // histogram blocks
#define AGG_LD 136 // aggH row stride in f16 (128 + 8 pad -> 2-way bank alias only)

typedef _Float16 f16x4 __attribute__((ext_vector_type(4)));
typedef float f32x4 __attribute__((ext_vector_type(4)));

// ---------------------------------------------------------------------------
// K1: two roles in one launch.
//   blocks [0,BBLK):       LDS bucket histogram -> reserve -> scatter (binning)
//   blocks [BBLK,+HBLK):   cnt_out no-return histogram at high occupancy
__global__ __launch_bounds__(256) void k_build(const int* __restrict__ ei, int E,
        int* __restrict__ cnt_out, int* __restrict__ bcnt,
        unsigned int* __restrict__ bkt, int NB) {
    __shared__ int h[MAXB];     // binning role only
    __shared__ int cur[MAXB];
    int tid = threadIdx.x;
    int E4 = E >> 2;
    const int4* src4 = (const int4*)ei;
    const int4* dst4 = (const int4*)(ei + E);

    if (blockIdx.x >= BBLK) {
        int gtid = (blockIdx.x - BBLK) * 256 + tid;
        int gstride = (gridDim.x - BBLK) * 256;
        for (int i = gtid; i < E4; i += gstride) {
            int4 s = src4[i];
            atomicAdd(&cnt_out[s.x], 1);
            atomicAdd(&cnt_out[s.y], 1);
            atomicAdd(&cnt_out[s.z], 1);
            atomicAdd(&cnt_out[s.w], 1);
        }
        for (int e = (E4 << 2) + gtid; e < E; e += gstride) {
            atomicAdd(&cnt_out[ei[e]], 1);
        }
        return;
    }

    int chunk4 = (E4 + BBLK - 1) / BBLK;
    int lo4 = blockIdx.x * chunk4;
    int hi4 = min(E4, lo4 + chunk4);
    bool last = (blockIdx.x == BBLK - 1);

    for (int k = tid; k < NB; k += 256) h[k] = 0;
    __syncthreads();

    for (int i = lo4 + tid; i < hi4; i += 256) {
        int4 d = dst4[i];
        atomicAdd(&h[d.x >> 4], 1);
        atomicAdd(&h[d.y >> 4], 1);
        atomicAdd(&h[d.z >> 4], 1);
        atomicAdd(&h[d.w >> 4], 1);
    }
    if (last) {
        for (int e = (E4 << 2) + tid; e < E; e += 256)
            atomicAdd(&h[ei[E + e] >> 4], 1);
    }
    __syncthreads();

    for (int k = tid; k < NB; k += 256) {
        int c = h[k];
        cur[k] = c ? atomicAdd(&bcnt[k], c) : 0;
    }
    __syncthreads();

    for (int i = lo4 + tid; i < hi4; i += 256) {
        int4 s = src4[i];
        int4 d = dst4[i];
        int p0 = atomicAdd(&cur[d.x >> 4], 1);
        int p1 = atomicAdd(&cur[d.y >> 4], 1);
        int p2 = atomicAdd(&cur[d.z >> 4], 1);
        int p3 = atomicAdd(&cur[d.w >> 4], 1);
        if (p0 < BCAP) bkt[(size_t)(d.x >> 4) * BCAP + p0] = (unsigned)s.x | ((unsigned)(d.x & 15) << 16);
        if (p1 < BCAP) bkt[(size_t)(d.y >> 4) * BCAP + p1] = (unsigned)s.y | ((unsigned)(d.y & 15) << 16);
        if (p2 < BCAP) bkt[(size_t)(d.z >> 4) * BCAP + p2] = (unsigned)s.z | ((unsigned)(d.z & 15) << 16);
        if (p3 < BCAP) bkt[(size_t)(d.w >> 4) * BCAP + p3] = (unsigned)s.w | ((unsigned)(d.w & 15) << 16);
    }
    if (last) {
        for (int e = (E4 << 2) + tid; e < E; e += 256) {
            int s = ei[e], dd = ei[E + e];
            int p = atomicAdd(&cur[dd >> 4], 1);
            if (p < BCAP) bkt[(size_t)(dd >> 4) * BCAP + p] = (unsigned)s | ((unsigned)(dd & 15) << 16);
        }
    }
}

// K2: rs_out = rsqrt(max(deg_out,1)); pack Wh[d][k] = (f16)W[d][k] (row-major)
__global__ __launch_bounds__(256) void k_rs(const int* __restrict__ cnt_out,
                                            float* __restrict__ rs_out,
                                            const float* __restrict__ W,
                                            __half2* __restrict__ Wh2, int N) {
    int i = blockIdx.x * blockDim.x + threadIdx.x;
    if (i < N) rs_out[i] = rsqrtf((float)max(cnt_out[i], 1));
    if (i < D * D / 2) {
        float2 w2 = ((const float2*)W)[i];
        Wh2[i] = __floats2half2_rn(w2.x, w2.y);
    }
}

// K3: feat_h[n][d] = (half)(feat[n][d] * rs_out[n])  (pre-scaled fp16)
__global__ __launch_bounds__(256) void k_prep(const float4* __restrict__ feat4,
                                              const float* __restrict__ rs_out,
                                              ushort4* __restrict__ feat_h,
                                              int total /* N*32 */) {
    int stride = gridDim.x * blockDim.x;
    for (int i = blockIdx.x * blockDim.x + threadIdx.x; i < total; i += stride) {
        int n = i >> 5;
        float rs = rs_out[n];
        float4 f = feat4[i];
        __half2 lo = __floats2half2_rn(f.x * rs, f.y * rs);
        __half2 hi = __floats2half2_rn(f.z * rs, f.w * rs);
        ushort4 u;
        u.x = __half_as_ushort(__low2half(lo));
        u.y = __half_as_ushort(__high2half(lo));
        u.z = __half_as_ushort(__low2half(hi));
        u.w = __half_as_ushort(__high2half(hi));
        feat_h[i] = u;
    }
}

// K4: fused per-bucket LDS-bin ; gather ; MFMA GEMM ; residual ; LN ; ReLU
__global__ __launch_bounds__(256) void k_fused(
        const int* __restrict__ bcnt, const unsigned int* __restrict__ bkt,
        const __half2* __restrict__ feat_h, const _Float16* __restrict__ Wh,
        const float* __restrict__ bias, const float* __restrict__ gamma,
        const float* __restrict__ beta, const float* __restrict__ feat,
        float* __restrict__ out, int N) {
    __shared__ _Float16 aggH[TN * AGG_LD];   // 4.25 KB, padded rows
    __shared__ float redS[4][TN];
    __shared__ float redQ[4][TN];
    __shared__ unsigned int braw[BCAP];      // staged bucket edges, 3 KB
    __shared__ unsigned short blist[BCAP];   // srcs grouped by local node, 1.5 KB
    __shared__ int bstart[TN + 1];
    __shared__ int bfill[TN];
    __shared__ int bdeg[TN];

    int tid  = threadIdx.x;
    int wv   = tid >> 6;          // wave 0..3
    int lane = tid & 63;
    int l15  = lane & 15;
    int lg   = lane >> 4;         // 16-lane group 0..3

    // output columns owned by this wave: d = (wv*2+nb)*16 + l15
    int dA0 = (wv * 2 + 0) * 16 + l15;
    int dA1 = (wv * 2 + 1) * 16 + l15;
    float bd0 = bias[dA0],  bd1 = bias[dA1];
    float gd0 = gamma[dA0], gd1 = gamma[dA1];
    float bt0 = beta[dA0],  bt1 = beta[dA1];

    // preload B-fragments (constant across tiles): B[k][j]=W[d][k], k=kb*16+lg*4+i
    f16x4 Bf0[8], Bf1[8];
    #pragma unroll
    for (int kb = 0; kb < 8; ++kb) {
        Bf0[kb] = *reinterpret_cast<const f16x4*>(&Wh[(size_t)dA0 * D + kb * 16 + lg * 4]);
        Bf1[kb] = *reinterpret_cast<const f16x4*>(&Wh[(size_t)dA1 * D + kb * 16 + lg * 4]);
    }

    int ntiles = (N + TN - 1) / TN;
    for (int t = blockIdx.x; t < ntiles; t += gridDim.x) {
        int nbase = t * TN;
        __syncthreads();   // previous tile's readers done

        // ---- stage bucket & histogram by local node (dst & 15)
        if (tid < TN) { bdeg[tid] = 0; bfill[tid] = 0; }
        __syncthreads();
        int ecnt = min(bcnt[t], BCAP);
        for (int j = tid; j < ecnt; j += 256) {
            unsigned int v = bkt[(size_t)t * BCAP + j];   // coalesced
            braw[j] = v;
            atomicAdd(&bdeg[v >> 16], 1);                 // LDS atomic
        }
        __syncthreads();
        if (tid == 0) {
            int run = 0;
            #pragma unroll
            for (int i = 0; i < TN; ++i) { bstart[i] = run; run += bdeg[i]; }
            bstart[TN] = run;
        }
        __syncthreads();
        for (int j = tid; j < ecnt; j += 256) {
            unsigned int v = braw[j];
            int node = v >> 16;
            int slot = bstart[node] + atomicAdd(&bfill[node], 1);
            blist[slot] = (unsigned short)(v & 0xFFFF);
        }
        __syncthreads();

        // ---- gather: wave wv builds rows wv*4 .. wv*4+3 (f16 store to aggH)
        for (int i = 0; i < 4; ++i) {
            int li = wv * 4 + i;
            int n  = nbase + li;
            float2 acc = make_float2(0.0f, 0.0f);
            if (n < N) {
                int deg = bdeg[li];
                int st  = bstart[li];
                int m8  = deg & ~7;
                int j   = 0;
                for (; j < m8; j += 8) {
                    int ss[8];
                    #pragma unroll
                    for (int k = 0; k < 8; ++k) ss[k] = blist[st + j + k];  // LDS broadcast
                    __half2 hh[8];
                    #pragma unroll
                    for (int k = 0; k < 8; ++k)
                        hh[k] = feat_h[(size_t)ss[k] * 64 + lane];          // 8 in flight
                    #pragma unroll
                    for (int k = 0; k < 8; ++k) {
                        float2 f = __half22float2(hh[k]);
                        acc.x += f.x; acc.y += f.y;
                    }
                }
                for (; j < deg; ++j) {
                    int s = blist[st + j];
                    float2 f = __half22float2(feat_h[(size_t)s * 64 + lane]);
                    acc.x += f.x; acc.y += f.y;
                }
            }
            *reinterpret_cast<__half2*>(&aggH[li * AGG_LD + 2 * lane]) =
                __floats2half2_rn(acc.x, acc.y);
        }
        __syncthreads();

        // ---- MFMA GEMM: A = aggH (16x128 f16), B = Wh frags; D = 16x32/wave
        f32x4 acc0 = {0.0f, 0.0f, 0.0f, 0.0f};
        f32x4 acc1 = {0.0f, 0.0f, 0.0f, 0.0f};
        #pragma unroll
        for (int kb = 0; kb < 8; ++kb) {
            f16x4 a = *reinterpret_cast<const f16x4*>(&aggH[l15 * AGG_LD + kb * 16 + lg * 4]);
            acc0 = __builtin_amdgcn_mfma_f32_16x16x16f16(a, Bf0[kb], acc0, 0, 0, 0);
            acc1 = __builtin_amdgcn_mfma_f32_16x16x16f16(a, Bf1[kb], acc1, 0, 0, 0);
        }

        // ---- epilogue: bias, rs_in, residual; LN partial sums
        float rv0[4], rv1[4];
        #pragma unroll
        for (int r = 0; r < 4; ++r) {
            int m = lg * 4 + r;            // node row in tile (D-layout)
            int n = nbase + m;
            float f0 = 0.0f, f1 = 0.0f;
            if (n < N) {
                float rsin = rsqrtf((float)max(bdeg[m], 1));
                f0 = (acc0[r] + bd0) * rsin + feat[(size_t)n * D + dA0];
                f1 = (acc1[r] + bd1) * rsin + feat[(size_t)n * D + dA1];
            }
            rv0[r] = f0; rv1[r] = f1;
            float s = f0 + f1;
            float q = f0 * f0 + f1 * f1;
            s += __shfl_xor(s, 1);  q += __shfl_xor(q, 1);
            s += __shfl_xor(s, 2);  q += __shfl_xor(q, 2);
            s += __shfl_xor(s, 4);  q += __shfl_xor(q, 4);
            s += __shfl_xor(s, 8);  q += __shfl_xor(q, 8);
            if (l15 == 0) { redS[wv][m] = s; redQ[wv][m] = q; }
        }
        __syncthreads();

        #pragma unroll
        for (int r = 0; r < 4; ++r) {
            int m = lg * 4 + r;
            int n = nbase + m;
            if (n < N) {
                float S = redS[0][m] + redS[1][m] + redS[2][m] + redS[3][m];
                float Q = redQ[0][m] + redQ[1][m] + redQ[2][m] + redQ[3][m];
                float mu  = S * (1.0f / 128.0f);
                float var = Q * (1.0f / 128.0f) - mu * mu;
                float inv = rsqrtf(var + LN_EPS);
                float v0 = (rv0[r] - mu) * inv * gd0 + bt0;
                float v1 = (rv1[r] - mu) * inv * gd1 + bt1;
                out[(size_t)n * D + dA0] = fmaxf(v0, 0.0f);
                out[(size_t)n * D + dA1] = fmaxf(v1, 0.0f);
            }
        }
    }
}

// ---------------------------------------------------------------------------
extern "C" void kernel_launch(void* const* d_in, const int* in_sizes, int n_in,
                              void* d_out, int out_size, void* d_ws, size_t ws_size,
                              hipStream_t stream) {
    const float* feat  = (const float*)d_in[0];
    const int*   ei    = (const int*)  d_in[1];
    const float* W     = (const float*)d_in[2];
    const float* bias  = (const float*)d_in[3];
    const float* gamma = (const float*)d_in[4];
    const float* beta  = (const float*)d_in[5];
    float* out = (float*)d_out;

    const int N  = in_sizes[0] / D;
    const int E  = in_sizes[1] / 2;
    const int NB = (N + TN - 1) / TN;   // buckets = output tiles (<= MAXB)

    // workspace layout (4B words):
    // cnt_out[Np] | bcnt[NBp] | rs_out[Np] | Wh[D*D/2 words f16] |
    // bkt[NB*BCAP u32] | feat_h[N*D/2 words]        (~17 MB)
    const size_t Np  = ((size_t)N + 1023) & ~(size_t)1023;
    const size_t NBp = ((size_t)NB + 1023) & ~(size_t)1023;
    int*   cnt_out = (int*)d_ws;
    int*   bcnt    = cnt_out + Np;
    float* rs_out  = (float*)(bcnt + NBp);
    _Float16* Wh   = (_Float16*)(rs_out + Np);
    unsigned int* bkt = (unsigned int*)((int*)(rs_out + Np) + D * D / 2);
    ushort4* feat_h   = (ushort4*)(bkt + (size_t)NB * BCAP);

    hipMemsetAsync(d_ws, 0, (Np + NBp) * sizeof(int), stream);  // zero cnt_out + bcnt

    k_build<<<BBLK + HBLK, 256, 0, stream>>>(ei, E, cnt_out, bcnt, bkt, NB);
    int nblk = (max(N, D * D / 2) + 255) / 256;
    k_rs<<<nblk, 256, 0, stream>>>(cnt_out, rs_out, W, (__half2*)Wh, N);
    k_prep<<<2048, 256, 0, stream>>>((const float4*)feat, rs_out, feat_h, N * 32);
    k_fused<<<NB, 256, 0, stream>>>(bcnt, bkt,
                                    (const __half2*)feat_h, Wh, bias, gamma,
                                    beta, feat, out, N);
}